// Round 1
// baseline (117.024 us; speedup 1.0000x reference)
//
#include <hip/hip_runtime.h>
#include <math.h>

#define DIM 4096
#define NH 32
#define NKV 8
#define HD 128
#define NREP 4
#define SPLIT 128
#define CHMAX 256

// ---------------------------------------------------------------------------
// Kernel 1: q/k/v GEMV + fused RoPE.
// One wave computes a PAIR of rows (2p, 2p+1) so RoPE's (even,odd) coupling
// stays inside the wave. 6144 rows total -> 3072 wave-tasks -> 768 blocks.
// ---------------------------------------------------------------------------
__global__ __launch_bounds__(256) void qkv_rope_kernel(
    const float* __restrict__ x, const float* __restrict__ fc,
    const float* __restrict__ fs, const float* __restrict__ wq,
    const float* __restrict__ wk, const float* __restrict__ wv,
    float* __restrict__ q_rope, float* __restrict__ k_new,
    float* __restrict__ v_new) {
  int wave = blockIdx.x * 4 + (threadIdx.x >> 6);
  int lane = threadIdx.x & 63;
  const float* W;
  float* dst;
  int r0;
  bool rope;
  if (wave < 2048) {            // q: 4096 rows
    W = wq; dst = q_rope; r0 = wave * 2; rope = true;
  } else if (wave < 2560) {     // k: 1024 rows
    W = wk; dst = k_new; r0 = (wave - 2048) * 2; rope = true;
  } else {                      // v: 1024 rows
    W = wv; dst = v_new; r0 = (wave - 2560) * 2; rope = false;
  }
  const float4* x4 = (const float4*)x;
  const float4* w0 = (const float4*)(W + (size_t)r0 * DIM);
  const float4* w1 = (const float4*)(W + (size_t)(r0 + 1) * DIM);
  float a0 = 0.f, a1 = 0.f;
  for (int c = lane; c < DIM / 4; c += 64) {
    float4 xv = x4[c];
    float4 u = w0[c];
    float4 v = w1[c];
    a0 += xv.x * u.x + xv.y * u.y + xv.z * u.z + xv.w * u.w;
    a1 += xv.x * v.x + xv.y * v.y + xv.z * v.z + xv.w * v.w;
  }
  for (int off = 32; off > 0; off >>= 1) {
    a0 += __shfl_down(a0, off, 64);
    a1 += __shfl_down(a1, off, 64);
  }
  if (lane == 0) {
    if (rope) {
      int j = (r0 & (HD - 1)) >> 1;   // pair index within head
      float c = fc[j], s = fs[j];
      dst[r0]     = a0 * c - a1 * s;
      dst[r0 + 1] = a0 * s + a1 * c;
    } else {
      dst[r0]     = a0;
      dst[r0 + 1] = a1;
    }
  }
}

// ---------------------------------------------------------------------------
// Kernel 2: flash-decode partials. Block = (kv head g, split). Each block
// computes scores+softmax+PV for its chunk of positions for ALL 4 q-heads of
// its kv head (so K/V are read exactly once from HBM).
// 256 threads = 4 waves x 4 groups x 16 lanes; a 16-lane group owns one
// position per iteration (512B contiguous K/V read), lane owns an 8-float
// d-slice.
// ---------------------------------------------------------------------------
__global__ __launch_bounds__(256) void attn_partial_kernel(
    const float* __restrict__ q_rope, const float* __restrict__ k_cache,
    const float* __restrict__ v_cache, const float* __restrict__ k_new,
    const float* __restrict__ v_new, float* __restrict__ partial_m,
    float* __restrict__ partial_l, float* __restrict__ partial_o,
    int start_pos, int T, int CH) {
  int g = blockIdx.x / SPLIT;
  int split = blockIdx.x % SPLIT;
  int t0 = split * CH;
  int tid = threadIdx.x;
  int wv = tid >> 6;     // wave 0..3
  int lane = tid & 63;
  int grp = lane >> 4;   // group 0..3 (position within iteration)
  int lig = lane & 15;   // lane-in-group (d-slice owner)

  __shared__ float s_sc[4][CHMAX];       // scores -> probs
  __shared__ float s_wacc[4][4][HD];     // per-wave V partials

  // preload q fragments for this lane's d-slice, all 4 heads
  float qf[4][8];
  int dbase = lig * 8;
#pragma unroll
  for (int h = 0; h < 4; ++h)
#pragma unroll
    for (int e = 0; e < 8; ++e)
      qf[h][e] = q_rope[(g * NREP + h) * HD + dbase + e];

  const float scale = 0.08838834764831845f;  // 1/sqrt(128)
  int iters = CH >> 4;  // 16 positions per block-iteration

  // ---- pass 1: scores ----
  for (int i = 0; i < iters; ++i) {
    int tl = i * 16 + wv * 4 + grp;
    int t = t0 + tl;
    float sh[4] = {0.f, 0.f, 0.f, 0.f};
    bool valid = (t < T);
    if (valid) {
      const float* kp = (t < start_pos)
                            ? (k_cache + ((size_t)t * NKV + g) * HD)
                            : (k_new + (size_t)g * HD);
      float4 A = *(const float4*)(kp + dbase);
      float4 B = *(const float4*)(kp + dbase + 4);
#pragma unroll
      for (int h = 0; h < 4; ++h) {
        sh[h] = A.x * qf[h][0] + A.y * qf[h][1] + A.z * qf[h][2] +
                A.w * qf[h][3] + B.x * qf[h][4] + B.y * qf[h][5] +
                B.z * qf[h][6] + B.w * qf[h][7];
      }
    }
#pragma unroll
    for (int h = 0; h < 4; ++h) {
#pragma unroll
      for (int m = 1; m < 16; m <<= 1) sh[h] += __shfl_xor(sh[h], m, 64);
    }
    if (lig == 0) {
#pragma unroll
      for (int h = 0; h < 4; ++h)
        s_sc[h][tl] = valid ? sh[h] * scale : -1e30f;
    }
  }
  __syncthreads();

  // ---- softmax stats: wave wv owns head wv ----
  {
    int h = wv;
    float m = -1e30f;
    for (int idx = lane; idx < CH; idx += 64) m = fmaxf(m, s_sc[h][idx]);
    for (int off = 32; off > 0; off >>= 1)
      m = fmaxf(m, __shfl_xor(m, off, 64));
    float l = 0.f;
    for (int idx = lane; idx < CH; idx += 64) {
      float p = __expf(s_sc[h][idx] - m);
      s_sc[h][idx] = p;
      l += p;
    }
    for (int off = 32; off > 0; off >>= 1) l += __shfl_xor(l, off, 64);
    if (lane == 0) {
      int hg = g * NREP + h;
      partial_m[hg * SPLIT + split] = m;
      partial_l[hg * SPLIT + split] = l;
    }
  }
  __syncthreads();

  // ---- pass 2: PV accumulation ----
  float acc[4][8];
#pragma unroll
  for (int h = 0; h < 4; ++h)
#pragma unroll
    for (int e = 0; e < 8; ++e) acc[h][e] = 0.f;

  for (int i = 0; i < iters; ++i) {
    int tl = i * 16 + wv * 4 + grp;
    int t = t0 + tl;
    if (t < T) {
      const float* vp = (t < start_pos)
                            ? (v_cache + ((size_t)t * NKV + g) * HD)
                            : (v_new + (size_t)g * HD);
      float4 A = *(const float4*)(vp + dbase);
      float4 B = *(const float4*)(vp + dbase + 4);
#pragma unroll
      for (int h = 0; h < 4; ++h) {
        float p = s_sc[h][tl];
        acc[h][0] += p * A.x; acc[h][1] += p * A.y;
        acc[h][2] += p * A.z; acc[h][3] += p * A.w;
        acc[h][4] += p * B.x; acc[h][5] += p * B.y;
        acc[h][6] += p * B.z; acc[h][7] += p * B.w;
      }
    }
  }
  // combine the 4 groups within each wave (lanes xor 16/32 share d-slice)
#pragma unroll
  for (int h = 0; h < 4; ++h)
#pragma unroll
    for (int e = 0; e < 8; ++e) {
      acc[h][e] += __shfl_xor(acc[h][e], 16, 64);
      acc[h][e] += __shfl_xor(acc[h][e], 32, 64);
    }
  if (grp == 0) {
#pragma unroll
    for (int h = 0; h < 4; ++h)
#pragma unroll
      for (int e = 0; e < 8; ++e) s_wacc[wv][h][dbase + e] = acc[h][e];
  }
  __syncthreads();
  // combine the 4 waves, write partials
  for (int o = tid; o < NREP * HD; o += 256) {
    int h = o >> 7, d = o & (HD - 1);
    float sum = s_wacc[0][h][d] + s_wacc[1][h][d] + s_wacc[2][h][d] +
                s_wacc[3][h][d];
    int hg = g * NREP + h;
    partial_o[((size_t)hg * SPLIT + split) * HD + d] = sum;
  }
}

// ---------------------------------------------------------------------------
// Kernel 3: combine splits. One block (128 threads) per head.
// ---------------------------------------------------------------------------
__global__ __launch_bounds__(128) void combine_kernel(
    const float* __restrict__ partial_m, const float* __restrict__ partial_l,
    const float* __restrict__ partial_o, float* __restrict__ attn_out) {
  int h = blockIdx.x;
  int tid = threadIdx.x;
  __shared__ float s_m[SPLIT], s_l[SPLIT], s_w[SPLIT];
  s_m[tid] = partial_m[h * SPLIT + tid];
  s_l[tid] = partial_l[h * SPLIT + tid];
  __syncthreads();
  float M = -1e30f;
  for (int s = 0; s < SPLIT; ++s) M = fmaxf(M, s_m[s]);
  s_w[tid] = __expf(s_m[tid] - M);
  __syncthreads();
  float L = 0.f;
  for (int s = 0; s < SPLIT; ++s) L += s_l[s] * s_w[s];
  float acc = 0.f;
  for (int s = 0; s < SPLIT; ++s)
    acc += s_w[s] * partial_o[((size_t)h * SPLIT + s) * HD + tid];
  attn_out[h * HD + tid] = acc / L;
}

// ---------------------------------------------------------------------------
// Kernel 4: out = attn @ wo.T  (wo row-major (DIM, NH*HD), row contiguous)
// ---------------------------------------------------------------------------
__global__ __launch_bounds__(256) void out_gemv_kernel(
    const float* __restrict__ attn, const float* __restrict__ wo,
    float* __restrict__ out) {
  int row = blockIdx.x * 4 + (threadIdx.x >> 6);
  int lane = threadIdx.x & 63;
  const float4* a4 = (const float4*)attn;
  const float4* w4 = (const float4*)(wo + (size_t)row * DIM);
  float a = 0.f;
  for (int c = lane; c < DIM / 4; c += 64) {
    float4 av = a4[c];
    float4 wv = w4[c];
    a += av.x * wv.x + av.y * wv.y + av.z * wv.z + av.w * wv.w;
  }
  for (int off = 32; off > 0; off >>= 1) a += __shfl_down(a, off, 64);
  if (lane == 0) out[row] = a;
}

extern "C" void kernel_launch(void* const* d_in, const int* in_sizes, int n_in,
                              void* d_out, int out_size, void* d_ws,
                              size_t ws_size, hipStream_t stream) {
  const float* x       = (const float*)d_in[0];
  const float* fc      = (const float*)d_in[1];
  const float* fs      = (const float*)d_in[2];
  const float* k_cache = (const float*)d_in[3];
  const float* v_cache = (const float*)d_in[4];
  const float* wq      = (const float*)d_in[5];
  const float* wk      = (const float*)d_in[6];
  const float* wv      = (const float*)d_in[7];
  const float* wo      = (const float*)d_in[8];
  float* out = (float*)d_out;

  int start_pos = in_sizes[3] / (NKV * HD);  // cache length
  int T = start_pos + 1;
  int CH = ((T + SPLIT - 1) / SPLIT + 15) & ~15;  // = 256 for T=32768

  float* ws = (float*)d_ws;
  float* q_rope    = ws;            // 4096
  float* k_new     = ws + 4096;     // 1024
  float* v_new     = ws + 5120;     // 1024
  float* attn_out  = ws + 6144;     // 4096
  float* partial_m = ws + 10240;    // 32*128
  float* partial_l = ws + 14336;    // 32*128
  float* partial_o = ws + 18432;    // 32*128*128

  qkv_rope_kernel<<<768, 256, 0, stream>>>(x, fc, fs, wq, wk, wv, q_rope,
                                           k_new, v_new);
  attn_partial_kernel<<<NKV * SPLIT, 256, 0, stream>>>(
      q_rope, k_cache, v_cache, k_new, v_new, partial_m, partial_l, partial_o,
      start_pos, T, CH);
  combine_kernel<<<NH, SPLIT, 0, stream>>>(partial_m, partial_l, partial_o,
                                           attn_out);
  out_gemv_kernel<<<1024, 256, 0, stream>>>(attn_out, wo, out);
}